// Round 3
// baseline (349.573 us; speedup 1.0000x reference)
//
#include <hip/hip_runtime.h>
#include <math.h>

// ChannelDropout, split in two:
//   A) scale[row] for all B*C rows: one thread per row, centers staged in LDS.
//   B) out[row, :] = x[row, :] * scale[row]: barrier-free float4 streamer,
//      one block per row; scale[] (70 KB) stays L2-hot from kernel A.
//
// scale = (valid && dist(pos, center0) > 0.1) ? 1/(mean_{c=1..N-1}(dist_c > 0.1) + 1e-8) : 0
// valid = !(pos == (-2,-2))

typedef float vfloat4 __attribute__((ext_vector_type(4)));  // native vector: OK for nontemporal builtins

#define MAX_CENTER_FLOATS 512  // 2*ncenters must fit (ncenters = 101 -> 202)

__global__ __launch_bounds__(256) void ChannelDropout_scale_kernel(
    const float* __restrict__ pos,
    const float* __restrict__ centers,
    float* __restrict__ scale,
    int rows, int ncenters)
{
    __shared__ float sc[MAX_CENTER_FLOATS];
    const int nfl = 2 * ncenters;
    for (int i = threadIdx.x; i < nfl; i += 256) sc[i] = centers[i];
    __syncthreads();

    const int row = blockIdx.x * 256 + threadIdx.x;
    if (row >= rows) return;

    const float px = pos[2 * row];
    const float py = pos[2 * row + 1];
    const bool valid = !(px == -2.0f && py == -2.0f);

    float cnt = 0.0f;
    for (int c = 1; c < ncenters; ++c) {
        const float dx = px - sc[2 * c];
        const float dy = py - sc[2 * c + 1];
        // match np: sqrt(dx*dx + dy*dy), no fma contraction
        const float d = sqrtf(__fadd_rn(__fmul_rn(dx, dx), __fmul_rn(dy, dy)));
        cnt += (d > 0.1f) ? 1.0f : 0.0f;
    }
    const float dx0 = px - sc[0];
    const float dy0 = py - sc[1];
    const bool kept0 =
        sqrtf(__fadd_rn(__fmul_rn(dx0, dx0), __fmul_rn(dy0, dy0))) > 0.1f;
    const float prob = cnt / (float)(ncenters - 1);
    scale[row] = (valid && kept0) ? (1.0f / (prob + 1e-8f)) : 0.0f;
}

__global__ __launch_bounds__(256) void ChannelDropout_apply_kernel(
    const float* __restrict__ x,
    const float* __restrict__ scale,
    float* __restrict__ out,
    int tlen)
{
    const int row = blockIdx.x;
    const float s = scale[row];  // same address across wave -> broadcast, L2-hot

    const size_t base = (size_t)row * (size_t)tlen;
    const int t4 = tlen >> 2;  // 750 float4 per row (3000 % 4 == 0)
    const vfloat4* __restrict__ xr = (const vfloat4*)(x + base);
    vfloat4* __restrict__ orow = (vfloat4*)(out + base);

    for (int i = threadIdx.x; i < t4; i += 256) {
        vfloat4 v = __builtin_nontemporal_load(&xr[i]);
        v *= s;
        __builtin_nontemporal_store(v, &orow[i]);
    }
    // tail (tlen % 4 != 0) — not taken for tlen = 3000
    for (int i = (t4 << 2) + (int)threadIdx.x; i < tlen; i += 256) {
        out[base + i] = x[base + i] * s;
    }
}

extern "C" void kernel_launch(void* const* d_in, const int* in_sizes, int n_in,
                              void* d_out, int out_size, void* d_ws, size_t ws_size,
                              hipStream_t stream) {
    const float* x       = (const float*)d_in[0];   // [B, C, T]
    const float* pos     = (const float*)d_in[1];   // [B, C, 2]
    const float* centers = (const float*)d_in[2];   // [N, 2]
    float* out = (float*)d_out;
    float* scale = (float*)d_ws;                    // rows floats (70 KB)

    const int rows     = in_sizes[1] / 2;       // B*C = 17600
    const int tlen     = in_sizes[0] / rows;    // T = 3000
    const int ncenters = in_sizes[2] / 2;       // 101

    const int sblocks = (rows + 255) / 256;
    ChannelDropout_scale_kernel<<<sblocks, 256, 0, stream>>>(
        pos, centers, scale, rows, ncenters);
    ChannelDropout_apply_kernel<<<rows, 256, 0, stream>>>(
        x, scale, out, tlen);
}